// Round 4
// baseline (26204.288 us; speedup 1.0000x reference)
//
#include <hip/hip_runtime.h>
#include <math.h>

// ---------------- problem constants ----------------
#define T_LEN 2048
#define NGRP  8      // batch groups (16 batches each)
#define NSLC  32     // blocks per group (8 hidden units per layer per block)
#define BPG   16     // batches per group (full MFMA N-dim)
#define NTH   512    // 8 waves

typedef __attribute__((ext_vector_type(8))) short short8v;  // 8 bf16
typedef __attribute__((ext_vector_type(4))) float f32x4;
typedef unsigned int u32t;
typedef unsigned long long u64t;

// ---------------- ws layout (u64 units) ----------------
// tagged h element: (tag<<32) | (bf16hi<<16) | bf16lo ; tag = step + 16
#define H1_OFF  0           // [4 slots][8 groups][16 batch][256 hid] u64 (1 MB)
#define H2_OFF  131072      // same (1 MB)
#define ABT_OFF 262144
#define WS_U64  262145      // ~2.1 MB total

// ---------------- LDS byte offsets ----------------
// staging: [2 pp][2 mat(h1,h2)][2 plane(hi,lo)][16 rows][512 B], XOR-swizzled
#define STG_SZ   65536
#define PART_OFF 65536      // [4 pairs][64 lanes][16 B]
#define FCP_OFF  69632      // [64 lanes][16 B]
// allocate 131072 dynamic -> exactly 1 block/CU

__device__ __forceinline__ float sigm(float x) { return 1.0f / (1.0f + expf(-x)); }

__device__ __forceinline__ u32t bf_rn(float x) {
  u32t b; __builtin_memcpy(&b, &x, 4);
  return (b + 0x7FFFu + ((b >> 16) & 1u)) >> 16;
}
__device__ __forceinline__ void split_bf(float x, u32t& hi, u32t& lo) {
  hi = bf_rn(x);
  u32t hb = hi << 16; float hf; __builtin_memcpy(&hf, &hb, 4);
  lo = bf_rn(x - hf);
}

__global__ void init_ws_kernel(u64t* ws) {
  for (int i = blockIdx.x * blockDim.x + threadIdx.x; i < WS_U64;
       i += gridDim.x * blockDim.x)
    ws[i] = 0ull;
}

#define MFMA16(a, b, c) __builtin_amdgcn_mfma_f32_16x16x32_bf16(a, b, c, 0, 0, 0)

__launch_bounds__(NTH, 2)
__global__ void lstm_persist(const float* __restrict__ y,
                             const float* __restrict__ Wih0, const float* __restrict__ Whh0,
                             const float* __restrict__ bih0, const float* __restrict__ bhh0,
                             const float* __restrict__ Wih1, const float* __restrict__ Whh1,
                             const float* __restrict__ bih1, const float* __restrict__ bhh1,
                             const float* __restrict__ Wfc, const float* __restrict__ bfc,
                             float* __restrict__ out, u64t* wsu) {
  extern __shared__ char lds[];
  const int tid   = threadIdx.x;
  const int lane  = tid & 63;
  const int wid   = tid >> 6;
  const int group = blockIdx.x & 7;    // stride-8 blockIdx -> same XCD per group
  const int slice = blockIdx.x >> 3;   // 0..31

  u64t* h1b    = wsu + H1_OFF;
  u64t* h2b    = wsu + H2_OFF;
  u64t* abortf = wsu + ABT_OFF;

  // zero staging LDS (both ping-pong slots = initial h zeros)
  for (int i = tid; i < STG_SZ / 4; i += NTH) ((u32t*)lds)[i] = 0;

  // ---- wave roles ----
  const bool isL1 = (wid >= 4);
  const int  tl   = (wid & 3) >> 1;        // tile 0/1
  const int  kh   = wid & 1;               // L0: k-half; L1: matrix (0=Wih1/h1, 1=Whh1/h2)
  const int  hidb = slice * 8 + tl * 4;

  // ---- A-fragment preload (split hi/lo bf16) ----
  const int m = lane & 15, kq4 = lane >> 4;
  const int gateA = m & 3, hs4A = m >> 2;       // row m = hs4*4 + gate
  const int growA = gateA * 256 + hidb + hs4A;

  short8v ahi[8], alo[8];
  if (!isL1) {
    const int ksb = kh * 4;
    #pragma unroll
    for (int ksl = 0; ksl < 4; ++ksl) {
      short8v h8, l8;
      #pragma unroll
      for (int j = 0; j < 8; ++j) {
        int k = (ksb + ksl) * 32 + kq4 * 8 + j;
        u32t hi, lo; split_bf(Whh0[growA * 256 + k], hi, lo);
        h8[j] = (short)hi; l8[j] = (short)lo;
      }
      ahi[ksl] = h8; alo[ksl] = l8;
    }
  } else {
    const float* WA = kh ? Whh1 : Wih1;
    #pragma unroll
    for (int ksl = 0; ksl < 8; ++ksl) {
      short8v h8, l8;
      #pragma unroll
      for (int j = 0; j < 8; ++j) {
        int k = ksl * 32 + kq4 * 8 + j;
        u32t hi, lo; split_bf(WA[growA * 256 + k], hi, lo);
        h8[j] = (short)hi; l8[j] = (short)lo;
      }
      ahi[ksl] = h8; alo[ksl] = l8;
    }
  }

  // FC fragments: slice 0, waves 1 (ks 0-3) and 3 (ks 4-7)
  const bool fcw  = (slice == 0) && (wid == 1 || wid == 3);
  const int  fksb = (wid == 3) ? 4 : 0;
  short8v fhi[4], flo[4];
  if (fcw) {
    #pragma unroll
    for (int ksl = 0; ksl < 4; ++ksl) {
      short8v h8, l8;
      #pragma unroll
      for (int j = 0; j < 8; ++j) {
        int k = (fksb + ksl) * 32 + kq4 * 8 + j;
        float w = (m < 2) ? Wfc[m * 256 + k] : 0.f;
        u32t hi, lo; split_bf(w, hi, lo);
        h8[j] = (short)hi; l8[j] = (short)lo;
      }
      fhi[ksl] = h8; flo[ksl] = l8;
    }
  }

  // ---- per-lane epilogue preloads (even waves; C: col=lane&15, row=(lane>>4)*4+reg) ----
  const int hidC = hidb + kq4;        // hid for this lane's C column set
  float bias4[4] = {0, 0, 0, 0}, wx4[16];
  if (wid == 0 || wid == 2) {
    #pragma unroll
    for (int r = 0; r < 4; ++r) {
      int row = r * 256 + hidC;
      bias4[r] = bih0[row] + bhh0[row];
      #pragma unroll
      for (int kk = 0; kk < 4; ++kk) wx4[r * 4 + kk] = Wih0[row * 4 + kk];
    }
  } else if (wid == 4 || wid == 6) {
    #pragma unroll
    for (int r = 0; r < 4; ++r) {
      int row = r * 256 + hidC;
      bias4[r] = bih1[row] + bhh1[row];
    }
  }
  float bfc0 = 0.f, bfc1 = 0.f;
  if (slice == 0 && wid == 3) { bfc0 = bfc[0]; bfc1 = bfc[1]; }
  const float* yb = y + (group * BPG + m) * T_LEN;

  float cst = 0.f;     // cell state (c1 on waves 0,2; c2 on waves 4,6)

  // staging map: thread -> (batch row, 8 consecutive k elems)
  const int srow = tid >> 5;
  const int k0e  = (tid & 31) * 8;
  const int sxr  = (srow & 7) << 4;
  const int scb  = (tid & 31) * 16;

  __syncthreads();

  for (int p = 0; p <= T_LEN + 1; ++p) {
    const int  pp    = p & 1;
    const bool need1 = (p >= 1 && p <= T_LEN);
    const bool need2 = (p >= 2 && p <= T_LEN + 1);

    // ---- poll tagged h words (exact tag match), stale-only reload ----
    u64t v1[8], v2[8];
    {
      const u64t* s1 = h1b + (u64t)((p - 1) & 3) * 32768 + group * 4096 + srow * 256 + k0e;
      const u64t* s2 = h2b + (u64t)((p - 2) & 3) * 32768 + group * 4096 + srow * 256 + k0e;
      const u32t tg1 = (u32t)(p + 15), tg2 = (u32t)(p + 14);
      u32t st1 = need1 ? 0xFFu : 0u, st2 = need2 ? 0xFFu : 0u;
      int guard = 0;
      while (st1 | st2) {
        #pragma unroll
        for (int j = 0; j < 8; ++j)
          if (st1 & (1u << j))
            v1[j] = __hip_atomic_load(s1 + j, __ATOMIC_RELAXED, __HIP_MEMORY_SCOPE_AGENT);
        #pragma unroll
        for (int j = 0; j < 8; ++j)
          if (st2 & (1u << j))
            v2[j] = __hip_atomic_load(s2 + j, __ATOMIC_RELAXED, __HIP_MEMORY_SCOPE_AGENT);
        u32t n1 = 0, n2 = 0;
        #pragma unroll
        for (int j = 0; j < 8; ++j)
          if ((st1 & (1u << j)) && (u32t)(v1[j] >> 32) != tg1) n1 |= 1u << j;
        #pragma unroll
        for (int j = 0; j < 8; ++j)
          if ((st2 & (1u << j)) && (u32t)(v2[j] >> 32) != tg2) n2 |= 1u << j;
        st1 = n1; st2 = n2;
        if (st1 | st2) {
          ++guard;
          if (guard > (1 << 16)) {
            __hip_atomic_store(abortf, 1ull, __ATOMIC_RELAXED, __HIP_MEMORY_SCOPE_AGENT);
            break;
          }
          if ((guard & 63) == 0 &&
              __hip_atomic_load(abortf, __ATOMIC_RELAXED, __HIP_MEMORY_SCOPE_AGENT) != 0)
            break;
        }
      }
    }

    // y prefetch (issued early, consumed in epilogue)
    float xx[4];
    if ((wid == 0 || wid == 2) && p < T_LEN) {
      #pragma unroll
      for (int kk = 0; kk < 4; ++kk) {
        int ti = p + kk - 3;
        xx[kk] = (ti >= 0) ? yb[ti] : -100.0f;
      }
    }

    // ---- unpack to swizzled LDS planes ----
    {
      char* base = lds + pp * 32768;
      if (need1) {
        short8v vh, vl;
        #pragma unroll
        for (int j = 0; j < 8; ++j) {
          u32t pk = (u32t)v1[j];
          vh[j] = (short)(pk >> 16); vl[j] = (short)(pk & 0xFFFFu);
        }
        *(short8v*)(base + srow * 512 + (scb ^ sxr))        = vh;
        *(short8v*)(base + 8192 + srow * 512 + (scb ^ sxr)) = vl;
      }
      if (need2) {
        short8v vh, vl;
        #pragma unroll
        for (int j = 0; j < 8; ++j) {
          u32t pk = (u32t)v2[j];
          vh[j] = (short)(pk >> 16); vl[j] = (short)(pk & 0xFFFFu);
        }
        *(short8v*)(base + 16384 + srow * 512 + (scb ^ sxr)) = vh;
        *(short8v*)(base + 24576 + srow * 512 + (scb ^ sxr)) = vl;
      }
    }
    __syncthreads();   // sync1: staging visible; also fences PART reuse

    // ---- MFMA (3-term split-precision) ----
    const int brow = lane & 15;
    const int bxr  = (brow & 7) << 4;
    const int bco  = (lane >> 4) * 16;
    char* sb = lds + pp * 32768;
#define BRD(mat, pl, ks) \
  (*(const short8v*)(sb + (mat) * 16384 + (pl) * 8192 + brow * 512 + ((((ks) * 64) + bco) ^ bxr)))

    f32x4 acc = {0.f, 0.f, 0.f, 0.f};
    if (!isL1) {
      if (p < T_LEN) {
        const int ksb = kh * 4;
        #pragma unroll
        for (int ksl = 0; ksl < 4; ++ksl) {
          short8v bh = BRD(0, 0, ksb + ksl), bl = BRD(0, 1, ksb + ksl);
          acc = MFMA16(ahi[ksl], bh, acc);
          acc = MFMA16(ahi[ksl], bl, acc);
          acc = MFMA16(alo[ksl], bh, acc);
        }
      }
    } else {
      if (p >= 1 && p <= T_LEN) {
        #pragma unroll
        for (int ksl = 0; ksl < 8; ++ksl) {
          short8v bh = kh ? BRD(1, 0, ksl) : BRD(0, 0, ksl);
          short8v bl = kh ? BRD(1, 1, ksl) : BRD(0, 1, ksl);
          acc = MFMA16(ahi[ksl], bh, acc);
          acc = MFMA16(ahi[ksl], bl, acc);
          acc = MFMA16(alo[ksl], bh, acc);
        }
      }
    }
    f32x4 accF = {0.f, 0.f, 0.f, 0.f};
    if (fcw && p >= 2) {
      #pragma unroll
      for (int ksl = 0; ksl < 4; ++ksl) {
        short8v bh = BRD(1, 0, fksb + ksl), bl = BRD(1, 1, fksb + ksl);
        accF = MFMA16(fhi[ksl], bh, accF);
        accF = MFMA16(fhi[ksl], bl, accF);
        accF = MFMA16(flo[ksl], bh, accF);
      }
    }

    // odd waves publish partials
    if (wid & 1) *(f32x4*)(lds + PART_OFF + (wid >> 1) * 1024 + lane * 16) = acc;
    if (fcw && wid == 1) *(f32x4*)(lds + FCP_OFF + lane * 16) = accF;
    __syncthreads();   // sync2

    // ---- even waves: reduce + nonlinearity + tagged h store (fire & forget) ----
    if (!(wid & 1)) {
      const bool act = isL1 ? (p >= 1 && p <= T_LEN) : (p < T_LEN);
      if (act) {
        f32x4 po = *(const f32x4*)(lds + PART_OFF + (wid >> 1) * 1024 + lane * 16);
        float g[4];
        #pragma unroll
        for (int r = 0; r < 4; ++r) g[r] = acc[r] + po[r] + bias4[r];
        if (!isL1) {
          #pragma unroll
          for (int kk = 0; kk < 4; ++kk)
            #pragma unroll
            for (int r = 0; r < 4; ++r) g[r] = fmaf(wx4[r * 4 + kk], xx[kk], g[r]);
        }
        cst = sigm(g[1]) * cst + sigm(g[0]) * tanhf(g[2]);
        float hv = sigm(g[3]) * tanhf(cst);
        u32t hi, lo; split_bf(hv, hi, lo);
        const u32t tag = (u32t)(isL1 ? (p + 15) : (p + 16));
        u64t pk = ((u64t)tag << 32) | (u64t)((hi << 16) | lo);
        u64t* dst = isL1
            ? (h2b + (u64t)((p - 1) & 3) * 32768 + group * 4096 + m * 256 + hidC)
            : (h1b + (u64t)(p & 3) * 32768 + group * 4096 + m * 256 + hidC);
        __hip_atomic_store(dst, pk, __ATOMIC_RELAXED, __HIP_MEMORY_SCOPE_AGENT);
      }
    }
    // FC finisher: wave 3 of slice 0
    if (wid == 3 && slice == 0 && p >= 2) {
      f32x4 pf = *(const f32x4*)(lds + FCP_OFF + lane * 16);
      if (lane < 16) {
        float2 o;
        o.x = accF[0] + pf[0] + bfc0;
        o.y = accF[1] + pf[1] + bfc1;
        *(float2*)(&out[(group * BPG + lane) * (T_LEN * 2) + (p - 2) * 2]) = o;
      }
    }
  }
}

extern "C" void kernel_launch(void* const* d_in, const int* in_sizes, int n_in,
                              void* d_out, int out_size, void* d_ws, size_t ws_size,
                              hipStream_t stream) {
  const float* y    = (const float*)d_in[0];
  const float* Wih0 = (const float*)d_in[1];
  const float* Whh0 = (const float*)d_in[2];
  const float* bih0 = (const float*)d_in[3];
  const float* bhh0 = (const float*)d_in[4];
  const float* Wih1 = (const float*)d_in[5];
  const float* Whh1 = (const float*)d_in[6];
  const float* bih1 = (const float*)d_in[7];
  const float* bhh1 = (const float*)d_in[8];
  const float* Wfc  = (const float*)d_in[9];
  const float* bfc  = (const float*)d_in[10];
  float* out = (float*)d_out;
  u64t*  ws  = (u64t*)d_ws;

  (void)hipFuncSetAttribute(reinterpret_cast<const void*>(lstm_persist),
                            hipFuncAttributeMaxDynamicSharedMemorySize, 131072);

  hipLaunchKernelGGL(init_ws_kernel, dim3(256), dim3(256), 0, stream, ws);
  hipLaunchKernelGGL(lstm_persist, dim3(NGRP * NSLC), dim3(NTH), 131072, stream,
                     y, Wih0, Whh0, bih0, bhh0, Wih1, Whh1, bih1, bhh1,
                     Wfc, bfc, out, ws);
}

// Round 5
// 8636.316 us; speedup vs baseline: 3.0342x; 3.0342x over previous
//
#include <hip/hip_runtime.h>
#include <math.h>

// ---------------- problem constants ----------------
#define T_LEN 2048
#define NGRP  8      // batch groups (16 batches each)
#define NSLC  32     // blocks per group (8 hidden/layer/block)
#define BPG   16     // batches per group (full MFMA N-dim)
#define NTH   512    // 8 waves

typedef __attribute__((ext_vector_type(8))) short short8v;  // 8 bf16
typedef __attribute__((ext_vector_type(4))) float f32x4;
typedef unsigned int u32t;
typedef unsigned long long u64t;

// ---------------- ws layout (u32 units) ----------------
// h element: packed u32 = (bf16hi<<16) | bf16lo
#define H1_OFF 0         // [2 slots][8 grp][16 batch][256 hid] u32
#define H2_OFF 65536
#define FLG_OFF 131072   // [8 grp][32 slices] u32 (one 128B line per group)
#define ABT_OFF 131328
#define WS_U32  131329

// ---------------- LDS (bytes) ----------------
// staging: [mat(h1,h2)][plane(hi,lo)][16 rows][512B], XOR-swizzled rows
// PART: publishers w1,w3,w4,w5 at 32768 + pi*2048 (2 tiles x 16B per lane)
// FCP:  w7 at 40960 (16B per lane)
// allocate 131072 dynamic -> exactly 1 block/CU

__device__ __forceinline__ float sigm(float x) { return 1.0f / (1.0f + expf(-x)); }

__device__ __forceinline__ u32t bf_rn(float x) {
  u32t b; __builtin_memcpy(&b, &x, 4);
  return (b + 0x7FFFu + ((b >> 16) & 1u)) >> 16;
}
__device__ __forceinline__ void split_bf(float x, u32t& hi, u32t& lo) {
  hi = bf_rn(x);
  u32t hb = hi << 16; float hf; __builtin_memcpy(&hf, &hb, 4);
  lo = bf_rn(x - hf);
}

__global__ void init_ws_kernel(u32t* ws) {
  for (int i = blockIdx.x * blockDim.x + threadIdx.x; i < WS_U32;
       i += gridDim.x * blockDim.x)
    ws[i] = 0u;
}

#define MFMA16(a, b, c) __builtin_amdgcn_mfma_f32_16x16x32_bf16(a, b, c, 0, 0, 0)

__launch_bounds__(NTH, 2)
__global__ void lstm_persist(const float* __restrict__ y,
                             const float* __restrict__ Wih0, const float* __restrict__ Whh0,
                             const float* __restrict__ bih0, const float* __restrict__ bhh0,
                             const float* __restrict__ Wih1, const float* __restrict__ Whh1,
                             const float* __restrict__ bih1, const float* __restrict__ bhh1,
                             const float* __restrict__ Wfc, const float* __restrict__ bfc,
                             float* __restrict__ out, u32t* wsu) {
  extern __shared__ char lds[];
  const int tid   = threadIdx.x;
  const int lane  = tid & 63;
  const int wid   = tid >> 6;
  const int group = blockIdx.x & 7;
  const int slice = blockIdx.x >> 3;

  u32t* h1b    = wsu + H1_OFF;
  u32t* h2b    = wsu + H2_OFF;
  u32t* flg    = wsu + FLG_OFF + group * 32;
  u32t* abortf = wsu + ABT_OFF;

  // zero staging (initial h = 0)
  for (int i = tid; i < 8192; i += NTH) ((u32t*)lds)[i] = 0;

  // ---- wave roles: w0/w1 L0(Whh0) K-halves; w2/w3 L1 Wih1(xh1); w4/w5 L1 Whh1(xh2);
  //                  w6/w7 FC (slice 0 only). Finishers: w0, w2, w6.
  const int  ksb   = (wid & 1) * 4;          // K-chunk base (x32)
  const int  mat   = (wid >= 4) ? 1 : 0;     // B source: 0=h1, 1=h2
  const bool isFC  = (wid >= 6);
  const bool fcAct = isFC && (slice == 0);

  const int m = lane & 15, kq4 = lane >> 4;

  // ---- A-fragment preload (split hi/lo bf16), 2 hid-tiles per wave ----
  short8v ahi[2][4], alo[2][4];
  if (!isFC) {
    const float* WA = (wid < 2) ? Whh0 : (wid < 4) ? Wih1 : Whh1;
    const int gate = m & 3, hs4 = m >> 2;
    #pragma unroll
    for (int t = 0; t < 2; ++t) {
      const int grow = gate * 256 + slice * 8 + t * 4 + hs4;
      #pragma unroll
      for (int ksl = 0; ksl < 4; ++ksl) {
        short8v h8, l8;
        #pragma unroll
        for (int j = 0; j < 8; ++j) {
          int k = (ksb + ksl) * 32 + kq4 * 8 + j;
          u32t hi, lo; split_bf(WA[grow * 256 + k], hi, lo);
          h8[j] = (short)hi; l8[j] = (short)lo;
        }
        ahi[t][ksl] = h8; alo[t][ksl] = l8;
      }
    }
  } else {
    #pragma unroll
    for (int ksl = 0; ksl < 4; ++ksl) {
      short8v h8, l8;
      #pragma unroll
      for (int j = 0; j < 8; ++j) {
        int k = (ksb + ksl) * 32 + kq4 * 8 + j;
        float w = (fcAct && m < 2) ? Wfc[m * 256 + k] : 0.f;
        u32t hi, lo; split_bf(w, hi, lo);
        h8[j] = (short)hi; l8[j] = (short)lo;
      }
      ahi[0][ksl] = h8; alo[0][ksl] = l8;
      ahi[1][ksl] = h8; alo[1][ksl] = l8;   // unused by FC
    }
  }

  // ---- epilogue preloads (finisher waves) ----
  float b4[2][4] = {{0, 0, 0, 0}, {0, 0, 0, 0}};
  float wx[2][16];
  if (wid == 0) {
    #pragma unroll
    for (int t = 0; t < 2; ++t)
      #pragma unroll
      for (int r = 0; r < 4; ++r) {
        int row = r * 256 + slice * 8 + t * 4 + kq4;
        b4[t][r] = bih0[row] + bhh0[row];
        #pragma unroll
        for (int kk = 0; kk < 4; ++kk) wx[t][r * 4 + kk] = Wih0[row * 4 + kk];
      }
  } else if (wid == 2) {
    #pragma unroll
    for (int t = 0; t < 2; ++t)
      #pragma unroll
      for (int r = 0; r < 4; ++r) {
        int row = r * 256 + slice * 8 + t * 4 + kq4;
        b4[t][r] = bih1[row] + bhh1[row];
      }
  }
  float bfc0 = 0.f, bfc1 = 0.f;
  if (wid == 6 && fcAct) { bfc0 = bfc[0]; bfc1 = bfc[1]; }
  const float* yb = y + (group * BPG + m) * T_LEN;

  float cst0 = 0.f, cst1 = 0.f;   // cell states (w0: c1 tiles; w2: c2 tiles)

  // staging map
  const int srow = tid >> 5;              // batch row 0..15
  const int sc8  = (tid & 31) * 8;        // hid start (u32 units)
  const int sxr  = (srow & 7) << 4;
  const int scb  = (tid & 31) * 16;       // byte col
  // B-read map
  const int brow = lane & 15;
  const int bxr  = (brow & 7) << 4;
  const int bco  = kq4 * 16;

  __syncthreads();

  for (int p = 0; p <= T_LEN + 1; ++p) {
    const bool need1 = (p >= 1 && p <= T_LEN);   // h1(p-1)
    const bool need2 = (p >= 2);                  // h2(p-2)

    // ---- S1: coherent loads of exchanged h ----
    u64t v1[4], v2[4];
    if (need1) {
      const u64t* s1 = (const u64t*)(h1b + ((p & 1) ^ 1) * 32768 + group * 4096 + srow * 256 + sc8);
      #pragma unroll
      for (int j = 0; j < 4; ++j)
        v1[j] = __hip_atomic_load(s1 + j, __ATOMIC_RELAXED, __HIP_MEMORY_SCOPE_AGENT);
    }
    if (need2) {
      const u64t* s2 = (const u64t*)(h2b + (p & 1) * 32768 + group * 4096 + srow * 256 + sc8);
      #pragma unroll
      for (int j = 0; j < 4; ++j)
        v2[j] = __hip_atomic_load(s2 + j, __ATOMIC_RELAXED, __HIP_MEMORY_SCOPE_AGENT);
    }
    // y prefetch (w0 epilogue input)
    float xx[4];
    if (wid == 0 && p < T_LEN) {
      #pragma unroll
      for (int kk = 0; kk < 4; ++kk) {
        int ti = p + kk - 3;
        xx[kk] = (ti >= 0) ? yb[ti] : -100.0f;
      }
    }

    // ---- unpack into swizzled LDS planes ----
    if (need1) {
      short8v vh, vl;
      #pragma unroll
      for (int j = 0; j < 4; ++j) {
        u32t e0 = (u32t)v1[j], e1 = (u32t)(v1[j] >> 32);
        vh[2 * j]     = (short)(e0 >> 16); vl[2 * j]     = (short)(e0 & 0xFFFFu);
        vh[2 * j + 1] = (short)(e1 >> 16); vl[2 * j + 1] = (short)(e1 & 0xFFFFu);
      }
      *(short8v*)(lds + srow * 512 + (scb ^ sxr))        = vh;
      *(short8v*)(lds + 8192 + srow * 512 + (scb ^ sxr)) = vl;
    }
    if (need2) {
      short8v vh, vl;
      #pragma unroll
      for (int j = 0; j < 4; ++j) {
        u32t e0 = (u32t)v2[j], e1 = (u32t)(v2[j] >> 32);
        vh[2 * j]     = (short)(e0 >> 16); vl[2 * j]     = (short)(e0 & 0xFFFFu);
        vh[2 * j + 1] = (short)(e1 >> 16); vl[2 * j + 1] = (short)(e1 & 0xFFFFu);
      }
      *(short8v*)(lds + 16384 + srow * 512 + (scb ^ sxr)) = vh;
      *(short8v*)(lds + 24576 + srow * 512 + (scb ^ sxr)) = vl;
    }
    __syncthreads();   // staging visible (also orders vs prev-phase reads)

    // ---- MFMA: 3-term split-precision, 2 tiles share each B-read ----
    bool act;
    if (wid < 2)      act = (p < T_LEN);
    else if (wid < 6) act = need1;
    else              act = fcAct && need2;

    f32x4 acc0 = {0.f, 0.f, 0.f, 0.f}, acc1 = {0.f, 0.f, 0.f, 0.f};
    if (act) {
      const char* sb = lds + mat * 16384;
      #pragma unroll
      for (int ksl = 0; ksl < 4; ++ksl) {
        const int kb = (ksb + ksl) * 64;
        short8v bh = *(const short8v*)(sb + brow * 512 + ((kb + bco) ^ bxr));
        short8v bl = *(const short8v*)(sb + 8192 + brow * 512 + ((kb + bco) ^ bxr));
        acc0 = MFMA16(ahi[0][ksl], bh, acc0);
        acc0 = MFMA16(ahi[0][ksl], bl, acc0);
        acc0 = MFMA16(alo[0][ksl], bh, acc0);
        if (!isFC) {
          acc1 = MFMA16(ahi[1][ksl], bh, acc1);
          acc1 = MFMA16(ahi[1][ksl], bl, acc1);
          acc1 = MFMA16(alo[1][ksl], bh, acc1);
        }
      }
    }

    // ---- publish partials ----
    if (wid == 1 || wid == 3 || wid == 4 || wid == 5) {
      const int pi = (wid == 1) ? 0 : (wid - 2);   // w3->1, w4->2, w5->3
      *(f32x4*)(lds + 32768 + pi * 2048 + lane * 32)      = acc0;
      *(f32x4*)(lds + 32768 + pi * 2048 + lane * 32 + 16) = acc1;
    } else if (wid == 7) {
      *(f32x4*)(lds + 40960 + lane * 16) = acc0;
    }
    __syncthreads();

    // ---- finishers: reduce + nonlinearity + h stores ----
    if (wid == 0 && p < T_LEN) {
      f32x4 q0 = *(const f32x4*)(lds + 32768 + lane * 32);
      f32x4 q1 = *(const f32x4*)(lds + 32768 + lane * 32 + 16);
      u32t* dbase = h1b + (p & 1) * 32768 + group * 4096 + m * 256 + slice * 8 + kq4;
      {
        float g[4];
        #pragma unroll
        for (int r = 0; r < 4; ++r) {
          g[r] = acc0[r] + q0[r] + b4[0][r];
          #pragma unroll
          for (int kk = 0; kk < 4; ++kk) g[r] = fmaf(wx[0][r * 4 + kk], xx[kk], g[r]);
        }
        cst0 = sigm(g[1]) * cst0 + sigm(g[0]) * tanhf(g[2]);
        float hv = sigm(g[3]) * tanhf(cst0);
        u32t hi, lo; split_bf(hv, hi, lo);
        __hip_atomic_store(dbase, (hi << 16) | lo, __ATOMIC_RELAXED, __HIP_MEMORY_SCOPE_AGENT);
      }
      {
        float g[4];
        #pragma unroll
        for (int r = 0; r < 4; ++r) {
          g[r] = acc1[r] + q1[r] + b4[1][r];
          #pragma unroll
          for (int kk = 0; kk < 4; ++kk) g[r] = fmaf(wx[1][r * 4 + kk], xx[kk], g[r]);
        }
        cst1 = sigm(g[1]) * cst1 + sigm(g[0]) * tanhf(g[2]);
        float hv = sigm(g[3]) * tanhf(cst1);
        u32t hi, lo; split_bf(hv, hi, lo);
        __hip_atomic_store(dbase + 4, (hi << 16) | lo, __ATOMIC_RELAXED, __HIP_MEMORY_SCOPE_AGENT);
      }
    } else if (wid == 2 && need1) {
      f32x4 p1a = *(const f32x4*)(lds + 34816 + lane * 32);
      f32x4 p1b = *(const f32x4*)(lds + 34816 + lane * 32 + 16);
      f32x4 p2a = *(const f32x4*)(lds + 36864 + lane * 32);
      f32x4 p2b = *(const f32x4*)(lds + 36864 + lane * 32 + 16);
      f32x4 p3a = *(const f32x4*)(lds + 38912 + lane * 32);
      f32x4 p3b = *(const f32x4*)(lds + 38912 + lane * 32 + 16);
      u32t* dbase = h2b + ((p & 1) ^ 1) * 32768 + group * 4096 + m * 256 + slice * 8 + kq4;
      {
        float g[4];
        #pragma unroll
        for (int r = 0; r < 4; ++r) g[r] = acc0[r] + p1a[r] + p2a[r] + p3a[r] + b4[0][r];
        cst0 = sigm(g[1]) * cst0 + sigm(g[0]) * tanhf(g[2]);
        float hv = sigm(g[3]) * tanhf(cst0);
        u32t hi, lo; split_bf(hv, hi, lo);
        __hip_atomic_store(dbase, (hi << 16) | lo, __ATOMIC_RELAXED, __HIP_MEMORY_SCOPE_AGENT);
      }
      {
        float g[4];
        #pragma unroll
        for (int r = 0; r < 4; ++r) g[r] = acc1[r] + p1b[r] + p2b[r] + p3b[r] + b4[1][r];
        cst1 = sigm(g[1]) * cst1 + sigm(g[0]) * tanhf(g[2]);
        float hv = sigm(g[3]) * tanhf(cst1);
        u32t hi, lo; split_bf(hv, hi, lo);
        __hip_atomic_store(dbase + 4, (hi << 16) | lo, __ATOMIC_RELAXED, __HIP_MEMORY_SCOPE_AGENT);
      }
    } else if (wid == 6 && fcAct && need2 && lane < 16) {
      f32x4 qf = *(const f32x4*)(lds + 40960 + lane * 16);
      float2 o;
      o.x = acc0[0] + qf[0] + bfc0;
      o.y = acc0[1] + qf[1] + bfc1;
      *(float2*)(&out[(group * BPG + lane) * (T_LEN * 2) + (p - 2) * 2]) = o;
    }

    if (p == T_LEN + 1) break;

    // ---- flag barrier (proven R3 protocol; w7-only poll + backoff) ----
    asm volatile("s_waitcnt vmcnt(0)" ::: "memory");   // h stores acked at coherence point
    __syncthreads();
    if (tid == 0)
      __hip_atomic_store(&flg[slice], (u32t)(p + 1), __ATOMIC_RELAXED, __HIP_MEMORY_SCOPE_AGENT);
    if (wid == 7) {
      const u32t tgt = (u32t)(p + 1);
      int guard = 0;
      for (;;) {
        u32t f = __hip_atomic_load(&flg[lane & 31], __ATOMIC_RELAXED, __HIP_MEMORY_SCOPE_AGENT);
        if (__all(f >= tgt)) break;
        if (++guard > (1 << 20)) {
          __hip_atomic_store(abortf, 1u, __ATOMIC_RELAXED, __HIP_MEMORY_SCOPE_AGENT);
          break;
        }
        if ((guard & 15) == 0 &&
            __hip_atomic_load(abortf, __ATOMIC_RELAXED, __HIP_MEMORY_SCOPE_AGENT) != 0)
          break;
        __builtin_amdgcn_s_sleep(1);
      }
    }
    __syncthreads();
  }
}

extern "C" void kernel_launch(void* const* d_in, const int* in_sizes, int n_in,
                              void* d_out, int out_size, void* d_ws, size_t ws_size,
                              hipStream_t stream) {
  const float* y    = (const float*)d_in[0];
  const float* Wih0 = (const float*)d_in[1];
  const float* Whh0 = (const float*)d_in[2];
  const float* bih0 = (const float*)d_in[3];
  const float* bhh0 = (const float*)d_in[4];
  const float* Wih1 = (const float*)d_in[5];
  const float* Whh1 = (const float*)d_in[6];
  const float* bih1 = (const float*)d_in[7];
  const float* bhh1 = (const float*)d_in[8];
  const float* Wfc  = (const float*)d_in[9];
  const float* bfc  = (const float*)d_in[10];
  float* out = (float*)d_out;
  u32t*  ws  = (u32t*)d_ws;

  (void)hipFuncSetAttribute(reinterpret_cast<const void*>(lstm_persist),
                            hipFuncAttributeMaxDynamicSharedMemorySize, 131072);

  hipLaunchKernelGGL(init_ws_kernel, dim3(256), dim3(256), 0, stream, ws);
  hipLaunchKernelGGL(lstm_persist, dim3(NGRP * NSLC), dim3(NTH), 131072, stream,
                     y, Wih0, Whh0, bih0, bhh0, Wih1, Whh1, bih1, bhh1,
                     Wfc, bfc, out, ws);
}